// Round 2
// baseline (173.682 us; speedup 1.0000x reference)
//
#include <hip/hip_runtime.h>
#include <stdint.h>

typedef __attribute__((ext_vector_type(8))) short short8;   // 8 x bf16 (4 VGPRs)
typedef __attribute__((ext_vector_type(4))) float f32x4;    // mfma C/D

#define NB 8
#define NQ 2048
#define NK 2048
#define ND 128
#define SCALE 0.08838834764831845f      // 1/sqrt(128)
#define L2E   1.4426950408889634f
#define NEGF  (-1.0e6f)

__device__ __forceinline__ uint32_t pk_bf16(float a, float b) {
  // RNE fp32 -> bf16, packed pair (low = a)
  uint32_t ua = __builtin_bit_cast(uint32_t, a);
  uint32_t ub = __builtin_bit_cast(uint32_t, b);
  ua += 0x7FFFu + ((ua >> 16) & 1u);
  ub += 0x7FFFu + ((ub >> 16) & 1u);
  return (ua >> 16) | (ub & 0xFFFF0000u);
}

// ---------------- V transpose+convert: V[b][k][d] (fp32) -> Vt[b][d][k] (bf16) ----------------
__global__ __launch_bounds__(256) void vtrans_kernel(const float* __restrict__ v,
                                                     ushort* __restrict__ vt) {
  __shared__ __align__(16) float tile[4096];   // 64 k-rows x 64 d fp32 (16 KB), 16B-chunk XOR swizzle
  char* sm = (char*)tile;
  const int t = threadIdx.x;
  const int bid = blockIdx.x;                  // 8 b * 32 k-blocks * 2 d-halves = 512 blocks
  const int b = bid >> 6;
  const int k0 = ((bid >> 1) & 31) << 6;
  const int d0 = (bid & 1) << 6;
#pragma unroll
  for (int i = 0; i < 4; ++i) {
    int id = i * 256 + t;                      // 1024 chunks of 16B (4 fp32)
    int k = id >> 4, c = id & 15;
    uint4 val = *(const uint4*)(v + (size_t)(b * NK + k0 + k) * ND + d0 + c * 4);
    *(uint4*)(sm + k * 256 + ((c ^ (k & 15)) * 16)) = val;
  }
  __syncthreads();
#pragma unroll
  for (int i = 0; i < 2; ++i) {
    int id = i * 256 + t;                      // 512 outputs of 16B (8 keys, bf16)
    int d = id >> 3, kc = id & 7;
    uint32_t w[4];
#pragma unroll
    for (int jj = 0; jj < 4; ++jj) {
      int kA = kc * 8 + jj * 2, kB = kA + 1;
      float fa = *(const float*)(sm + kA * 256 + (((d >> 2) ^ (kA & 15)) * 16) + (d & 3) * 4);
      float fb = *(const float*)(sm + kB * 256 + (((d >> 2) ^ (kB & 15)) * 16) + (d & 3) * 4);
      w[jj] = pk_bf16(fa, fb);
    }
    uint4 o; o.x = w[0]; o.y = w[1]; o.z = w[2]; o.w = w[3];
    *(uint4*)(vt + (size_t)(b * ND + d0 + d) * NK + k0 + kc * 8) = o;
  }
}

// ---------------- Flash attention ----------------
// 256 blocks (b, q-block of 64) x 256 threads. half = wave>>1 (key half), qg = wave&1 (q group of 32).
// S^T = K . Q^T (A=K tile LDS, B=Q regs); O^T = V^T . P^T (A=Vt tile LDS, B=P LDS scratch).
#define LDS_BYTES 40960
__global__ __launch_bounds__(256, 1) void attn_kernel(const float* __restrict__ qm,
                                                      const float* __restrict__ km,
                                                      const ushort* __restrict__ vtm,
                                                      const int* __restrict__ maskm,
                                                      float* __restrict__ outm) {
  __shared__ __align__(16) char sm[LDS_BYTES];
  // layout: [0,16384): K tiles bf16 (2 halves x 32keys x 128d, 16B-chunk swizzle c^(row&15))
  //         [16384,32768): Vt tiles bf16 (2 halves x 128d x 32keys, swizzle c^(row&3))
  //         [32768,40960): P scratch, 2KB/wave ([32 q][32 k] bf16, 8B-unit swizzle u^(r&6))
  const int bid = blockIdx.x;
  const int b  = bid >> 5;
  const int q0 = (bid & 31) << 6;
  const int t = threadIdx.x;
  const int lane = t & 63;
  const int wave = t >> 6;
  const int r = lane & 15;
  const int quad = lane >> 4;
  const int half = wave >> 1;
  const int qg = wave & 1;

  // Q fragments (B-operand): b[j] = Q[q=lane&15][d=quad*8+j], per (qtile, kstep). fp32 -> bf16 pack.
  short8 qf[2][4];
#pragma unroll
  for (int qt = 0; qt < 2; ++qt)
#pragma unroll
    for (int ks = 0; ks < 4; ++ks) {
      const float* p = qm + (size_t)(b * NQ + q0 + qg * 32 + qt * 16 + r) * ND + ks * 32 + quad * 8;
      f32x4 a = *(const f32x4*)p;
      f32x4 c = *(const f32x4*)(p + 4);
      uint4 u;
      u.x = pk_bf16(a[0], a[1]); u.y = pk_bf16(a[2], a[3]);
      u.z = pk_bf16(c[0], c[1]); u.w = pk_bf16(c[2], c[3]);
      qf[qt][ks] = __builtin_bit_cast(short8, u);
    }

  f32x4 oacc[2][8];
#pragma unroll
  for (int qt = 0; qt < 2; ++qt)
#pragma unroll
    for (int dt = 0; dt < 8; ++dt) oacc[qt][dt] = (f32x4){0.f, 0.f, 0.f, 0.f};
  float m_[2] = {-1e30f, -1e30f};
  float l_[2] = {0.f, 0.f};

  char* const pbase = sm + 32768 + wave * 2048;

  for (int it = 0; it < 32; ++it) {
    // ---- global loads (fp32 K, bf16 Vt) issued before barrier ----
    uint4 kv[4], vv[4];
#pragma unroll
    for (int i = 0; i < 4; ++i) {
      int id = i * 256 + t;                  // 1024 bf16-chunks: K tiles both halves
      int h = id >> 9, row = (id >> 4) & 31, c = id & 15;
      const float* p = km + (size_t)(b * NK + h * 1024 + it * 32 + row) * ND + c * 8;
      f32x4 a = *(const f32x4*)p;
      f32x4 cc = *(const f32x4*)(p + 4);
      kv[i].x = pk_bf16(a[0], a[1]);  kv[i].y = pk_bf16(a[2], a[3]);
      kv[i].z = pk_bf16(cc[0], cc[1]); kv[i].w = pk_bf16(cc[2], cc[3]);
    }
#pragma unroll
    for (int i = 0; i < 4; ++i) {
      int id = i * 256 + t;                  // 1024 chunks: Vt tiles both halves (bf16)
      int h = id >> 9, row = (id >> 2) & 127, c = id & 3;
      vv[i] = *(const uint4*)(vtm + (size_t)(b * ND + row) * NK + h * 1024 + it * 32 + c * 8);
    }
    int4 mv0 = *(const int4*)(maskm + b * NK + half * 1024 + it * 32 + quad * 4);
    int4 mv1 = *(const int4*)(maskm + b * NK + half * 1024 + it * 32 + 16 + quad * 4);

    __syncthreads();                         // prev iter done reading LDS
#pragma unroll
    for (int i = 0; i < 4; ++i) {
      int id = i * 256 + t;
      int h = id >> 9, row = (id >> 4) & 31, c = id & 15;
      *(uint4*)(sm + h * 8192 + row * 256 + ((c ^ (row & 15)) * 16)) = kv[i];
    }
#pragma unroll
    for (int i = 0; i < 4; ++i) {
      int id = i * 256 + t;
      int h = id >> 9, row = (id >> 2) & 127, c = id & 3;
      *(uint4*)(sm + 16384 + h * 8192 + row * 64 + ((c ^ (row & 3)) * 16)) = vv[i];
    }
    __syncthreads();                         // tiles staged

    // ---- S^T = K . Q^T ----
    short8 kf[2][4];                         // A-frag: a[j]=K[mt*16+r][ks*32+quad*8+j]
#pragma unroll
    for (int mt = 0; mt < 2; ++mt)
#pragma unroll
      for (int ks = 0; ks < 4; ++ks)
        kf[mt][ks] = *(const short8*)(sm + half * 8192 + (mt * 16 + r) * 256 + (((ks * 4 + quad) ^ r) * 16));
    f32x4 st[2][2];
#pragma unroll
    for (int mt = 0; mt < 2; ++mt)
#pragma unroll
      for (int qt = 0; qt < 2; ++qt) {
        f32x4 acc = (f32x4){0.f, 0.f, 0.f, 0.f};
#pragma unroll
        for (int ks = 0; ks < 4; ++ks)
          acc = __builtin_amdgcn_mfma_f32_16x16x32_bf16(kf[mt][ks], qf[qt][ks], acc, 0, 0, 0);
        st[mt][qt] = acc;                    // C: row=key=quad*4+reg (+mt*16), col=q=lane&15
      }

    // ---- online softmax per q-tile (stats per-column => per-lane scalar) ----
#pragma unroll
    for (int qt = 0; qt < 2; ++qt) {
      float s[2][4];
#pragma unroll
      for (int mt = 0; mt < 2; ++mt) {
        const int4 mv = mt ? mv1 : mv0;
        s[mt][0] = mv.x ? st[mt][qt][0] * SCALE : NEGF;
        s[mt][1] = mv.y ? st[mt][qt][1] * SCALE : NEGF;
        s[mt][2] = mv.z ? st[mt][qt][2] * SCALE : NEGF;
        s[mt][3] = mv.w ? st[mt][qt][3] * SCALE : NEGF;
      }
      float tm = s[0][0];
#pragma unroll
      for (int mt = 0; mt < 2; ++mt)
#pragma unroll
        for (int g = 0; g < 4; ++g) tm = fmaxf(tm, s[mt][g]);
      tm = fmaxf(tm, __shfl_xor(tm, 16));
      tm = fmaxf(tm, __shfl_xor(tm, 32));
      float mn = fmaxf(m_[qt], tm);
      float alpha = exp2f((m_[qt] - mn) * L2E);
      float p[2][4]; float ps = 0.f;
#pragma unroll
      for (int mt = 0; mt < 2; ++mt)
#pragma unroll
        for (int g = 0; g < 4; ++g) { p[mt][g] = exp2f((s[mt][g] - mn) * L2E); ps += p[mt][g]; }
      ps += __shfl_xor(ps, 16);
      ps += __shfl_xor(ps, 32);
      l_[qt] = l_[qt] * alpha + ps;
      m_[qt] = mn;
#pragma unroll
      for (int dt = 0; dt < 8; ++dt) oacc[qt][dt] *= alpha;
      // pack P (bf16) to per-wave LDS scratch: row q, 8B unit u=mt*4+quad (keys 4u..4u+3), swizzle u^(r&6)
#pragma unroll
      for (int mt = 0; mt < 2; ++mt) {
        uint2 w; w.x = pk_bf16(p[mt][0], p[mt][1]); w.y = pk_bf16(p[mt][2], p[mt][3]);
        *(uint2*)(pbase + (qt * 16 + r) * 64 + (((mt * 4 + quad) ^ (r & 6)) * 8)) = w;
      }
    }

    // ---- O^T += V^T . P^T ----
    short8 pf[2];                            // B-frag: b[j]=P[q=lane&15][key=quad*8+j]
#pragma unroll
    for (int qt = 0; qt < 2; ++qt)
      pf[qt] = *(const short8*)(pbase + (qt * 16 + r) * 64 + (((quad * 2) ^ (r & 6)) * 8));
#pragma unroll
    for (int dt = 0; dt < 8; ++dt) {
      short8 vf = *(const short8*)(sm + 16384 + half * 8192 + (dt * 16 + r) * 64 + ((quad ^ (r & 3)) * 16));
#pragma unroll
      for (int qt = 0; qt < 2; ++qt)
        oacc[qt][dt] = __builtin_amdgcn_mfma_f32_16x16x32_bf16(vf, pf[qt], oacc[qt][dt], 0, 0, 0);
    }
  }

  // ---- split-K merge (half 1 -> half 0) + fp32 epilogue ----
  __syncthreads();
  float* xch = (float*)(sm + qg * 17408) + lane * 68;   // 64 lanes x 68 floats per q-group
  if (half == 1) {
    xch[0] = m_[0]; xch[1] = m_[1]; xch[2] = l_[0]; xch[3] = l_[1];
#pragma unroll
    for (int qt = 0; qt < 2; ++qt)
#pragma unroll
      for (int dt = 0; dt < 8; ++dt)
        *(f32x4*)(xch + 4 + (qt * 8 + dt) * 4) = oacc[qt][dt];
  }
  __syncthreads();
  if (half == 0) {
#pragma unroll
    for (int qt = 0; qt < 2; ++qt) {
      float m1 = xch[qt], l1 = xch[2 + qt];
      float m12 = fmaxf(m_[qt], m1);
      float a0 = exp2f((m_[qt] - m12) * L2E);
      float a1 = exp2f((m1 - m12) * L2E);
      float linv = 1.0f / (a0 * l_[qt] + a1 * l1);
#pragma unroll
      for (int dt = 0; dt < 8; ++dt) {
        f32x4 o1 = *(const f32x4*)(xch + 4 + (qt * 8 + dt) * 4);
        f32x4 o = (oacc[qt][dt] * a0 + o1 * a1) * linv;
        *(f32x4*)(outm + (size_t)(b * NQ + q0 + qg * 32 + qt * 16 + r) * ND + dt * 16 + quad * 4) = o;
      }
    }
  }
}

extern "C" void kernel_launch(void* const* d_in, const int* in_sizes, int n_in,
                              void* d_out, int out_size, void* d_ws, size_t ws_size,
                              hipStream_t stream) {
  const float* q   = (const float*)d_in[0];   // fp32 [8,2048,128]
  const float* k   = (const float*)d_in[1];   // fp32 [8,2048,128]
  const float* v   = (const float*)d_in[2];   // fp32 [8,2048,128]
  const int*   msk = (const int*)d_in[3];     // int32 [8,2048]
  float* out = (float*)d_out;                 // fp32 [8,2048,128]
  ushort* vt = (ushort*)d_ws;                 // 4 MB: Vt[b][d][k] bf16

  vtrans_kernel<<<512, 256, 0, stream>>>(v, vt);
  attn_kernel<<<256, 256, 0, stream>>>(q, k, vt, msk, out);
}